// Round 4
// baseline (1022.511 us; speedup 1.0000x reference)
//
#include <hip/hip_runtime.h>

// Problem constants (match reference)
constexpr int   NVEC  = 131072;   // N
constexpr int   DIMC  = 128;      // latent dim
constexpr int   KC    = 4096;     // codebook size
constexpr float DECAYC = 0.99f;
constexpr float OMDECAY = 0.01f;
constexpr float EPSC  = 1e-5f;
// 3-term split product (ah.bh + al.bh + ah.bl): score error = al.bl,
// |err| <= 2^-16 * sum|x||e| ~ 1.3e-3 worst case. MARGIN = 16x worst case.
constexpr float MARGIN = 0.02f;

typedef __bf16 v8bf  __attribute__((ext_vector_type(8)));
typedef float  f32x16 __attribute__((ext_vector_type(16)));

// Async global->LDS 16B copy: dest = wave-uniform LDS base + lane*16.
__device__ __forceinline__ void async_copy16(const void* gp, void* lds_wave_base, int lane) {
#if __has_builtin(__builtin_amdgcn_global_load_lds)
    __builtin_amdgcn_global_load_lds(
        (const __attribute__((address_space(1))) unsigned int*)gp,
        (__attribute__((address_space(3))) unsigned int*)lds_wave_base, 16, 0, 0);
#else
    ((v8bf*)lds_wave_base)[lane] = *(const v8bf*)gp;
#endif
}

// ---------------- kernel S: split embed into bf16 hi/lo (transposed) + fused colnorm ----------------
__global__ __launch_bounds__(256) void split_e_kernel(const float* __restrict__ embed,
                                                      __bf16* __restrict__ ehT,
                                                      __bf16* __restrict__ elT,
                                                      float* __restrict__ nhe2) {
    __shared__ __bf16 sh_h[64 * 130];
    __shared__ __bf16 sh_l[64 * 130];
    __shared__ float  sh_n[4][64];
    const int tid = threadIdx.x;
    const int kbase = blockIdx.x * 64;
    const int kloc = tid & 63;
    float nacc = 0.f;
    for (int it = 0; it < 32; ++it) {
        int d = it * 4 + (tid >> 6);
        float v = embed[(size_t)d * KC + kbase + kloc];   // coalesced in k
        __bf16 h = (__bf16)v;
        __bf16 l = (__bf16)(v - (float)h);
        sh_h[kloc * 130 + d] = h;
        sh_l[kloc * 130 + d] = l;
        nacc = fmaf(v, v, nacc);
    }
    sh_n[tid >> 6][kloc] = nacc;
    __syncthreads();
    if (tid < 64)
        nhe2[kbase + tid] = -0.5f * (sh_n[0][tid] + sh_n[1][tid] + sh_n[2][tid] + sh_n[3][tid]);
    for (int it = 0; it < 32; ++it) {
        int idx = it * 256 + tid;
        int k = idx >> 7;
        int d = idx & 127;
        ehT[(size_t)(kbase + k) * DIMC + d] = sh_h[k * 130 + d];
        elT[(size_t)(kbase + k) * DIMC + d] = sh_l[k * 130 + d];
    }
}

// ---------------- kernel P1 v7: 32x32x16 MFMA split-bf16 GEMM + top-2 + fused flag/hist ----------------
// v5 structure (single-buffered, __syncthreads; round-3 explicit pipeline REGRESSED:
// +16KB LDS cut occupancy 3->2 blocks/CU, losing inter-wave overlap).
// 4 waves/block; wave owns ONE 32-row tile. Chunk = 64 cols x 128 k.
// mfma_f32_32x32x16_bf16: 2382 vs 2075 TF ubench -> ~17% less matrix-pipe time,
// half the MFMA issue slots (48 vs 96 per chunk-wave).
//   A-frag: row = lane&31, k = s*16 + (lane>>5)*8 + j
//   B-frag: col = lane&31, k = s*16 + (lane>>5)*8 + j
//   C/D   : col = lane&31, row = (reg&3) + 8*(reg>>2) + 4*(lane>>5)   [m74/m101]
// LDS slot-major granules: (ct, s, lane) at ct*512 + s*64 + lane -> fragment
// ds_read_b128 stride-1 in lane (conflict-free); ct/s fold into the immediate.
// Epilogue fuses flag-compaction and the histogram for unflagged rows.
__global__ __launch_bounds__(256, 3) void phase1_kernel(
    const float* __restrict__ x, const __bf16* __restrict__ ehT,
    const __bf16* __restrict__ elT, const float* __restrict__ nhe2,
    float* __restrict__ out_indf, int* __restrict__ ws_ind,
    int* __restrict__ ws_nflag, int* __restrict__ ws_list, int* __restrict__ cnt)
{
    __shared__ v8bf E[2048];    // [0..1023] = hi, [1024..2047] = lo  (32 KB)
    const int tid  = threadIdx.x;
    const int wave = tid >> 6;
    const int lane = tid & 63;
    const int cl   = lane & 31;     // col-in-tile (B/C) and row-in-tile (A)
    const int h    = lane >> 5;     // k-half
    const int rowBase = blockIdx.x * 128 + wave * 32;

    // A fragments: 8 k-slices of 16; hi + exact residual lo
    v8bf ah[8], al[8];
#pragma unroll
    for (int s = 0; s < 8; ++s) {
        const float* p = x + (size_t)(rowBase + cl) * DIMC + s * 16 + h * 8;
        float4 v0 = *reinterpret_cast<const float4*>(p);
        float4 v1 = *reinterpret_cast<const float4*>(p + 4);
        float vv[8] = {v0.x, v0.y, v0.z, v0.w, v1.x, v1.y, v1.z, v1.w};
        v8bf hh, ll;
#pragma unroll
        for (int j = 0; j < 8; ++j) {
            __bf16 hb = (__bf16)vv[j];
            hh[j] = hb;
            ll[j] = (__bf16)(vv[j] - (float)hb);
        }
        ah[s] = hh; al[s] = ll;
    }

    // Staging source offsets: dest granule D = i*256 + tid decomposes as
    // ct = D>>9, s = (D>>6)&7, half = (D>>5)&1, c = D&31; source element
    // (col = ct*32 + c, k = s*16 + half*8). Chunk-invariant; advance base.
    int soff[4];
#pragma unroll
    for (int i = 0; i < 4; ++i) {
        int D = i * 256 + tid;
        int ct = D >> 9, s = (D >> 6) & 7, hf = (D >> 5) & 1, c = D & 31;
        soff[i] = (ct * 32 + c) * DIMC + s * 16 + hf * 8;
    }
    const __bf16* ph = ehT;
    const __bf16* pl = elT;

    float b1[16], b2[16]; int i1[16];
#pragma unroll
    for (int r = 0; r < 16; ++r) { b1[r] = -3.4e38f; b2[r] = -3.4e38f; i1[r] = 0; }

    for (int chunk = 0; chunk < KC / 64; ++chunk) {
#pragma unroll
        for (int i = 0; i < 4; ++i) {
            async_copy16(ph + soff[i], &E[i * 256 + wave * 64], lane);
            async_copy16(pl + soff[i], &E[1024 + i * 256 + wave * 64], lane);
        }
        ph += (size_t)64 * DIMC;
        pl += (size_t)64 * DIMC;
        __syncthreads();

        const int cb = chunk * 64;
#pragma unroll
        for (int ct = 0; ct < 2; ++ct) {
            const float nh = nhe2[cb + ct * 32 + cl];   // L2-hot; uniform over all 16 slots
            f32x16 acc;
#pragma unroll
            for (int r = 0; r < 16; ++r) acc[r] = nh;
#pragma unroll
            for (int s = 0; s < 8; ++s) {
                v8bf bh = E[ct * 512 + s * 64 + lane];
                v8bf bl = E[1024 + ct * 512 + s * 64 + lane];
                acc = __builtin_amdgcn_mfma_f32_32x32x16_bf16(ah[s], bh, acc, 0, 0, 0);
                acc = __builtin_amdgcn_mfma_f32_32x32x16_bf16(al[s], bh, acc, 0, 0, 0);
                acc = __builtin_amdgcn_mfma_f32_32x32x16_bf16(ah[s], bl, acc, 0, 0, 0);
            }
            const int colG = cb + ct * 32 + cl;
#pragma unroll
            for (int r = 0; r < 16; ++r) {
                float sc = acc[r];
                float ob = b1[r];
                b2[r] = __builtin_amdgcn_fmed3f(ob, b2[r], sc);  // exact 2nd-best update
                b1[r] = fmaxf(ob, sc);
                i1[r] = (sc > ob) ? colG : i1[r];                 // strict: tie keeps earlier col
            }
        }
        __syncthreads();
    }

    // top-2 merge across the 32 col-lanes of each half (tie -> lowest index)
#pragma unroll
    for (int off = 1; off < 32; off <<= 1) {
#pragma unroll
        for (int r = 0; r < 16; ++r) {
            float ob1 = __shfl_xor(b1[r], off, 64);
            int   oi1 = __shfl_xor(i1[r], off, 64);
            float ob2 = __shfl_xor(b2[r], off, 64);
            if (ob1 > b1[r] || (ob1 == b1[r] && oi1 < i1[r])) {
                b2[r] = fmaxf(b1[r], ob2); b1[r] = ob1; i1[r] = oi1;
            } else {
                b2[r] = fmaxf(b2[r], ob1);
            }
        }
    }
    if (cl == 0) {
#pragma unroll
        for (int r = 0; r < 16; ++r) {
            int row = rowBase + (r & 3) + 8 * (r >> 2) + 4 * h;
            ws_ind[row]   = i1[r];
            out_indf[row] = (float)i1[r];
            if (b1[r] - b2[r] < MARGIN) {          // fused flag-compaction
                int p = atomicAdd(ws_nflag, 1);
                ws_list[p] = row;
            } else {
                atomicAdd(&cnt[i1[r]], 1);         // fused histogram (final ind)
            }
        }
    }
}

// ---------------- kernel R v3: exact fp32 rescore of flagged rows (16 rows/block) ----------------
// ev loads batched 8-wide: cuts the serial d-chain of 1 VMEM load per 16 FMAs
// (latency-bound at L2/L3) to 1 batch of 8 loads per 128 FMAs.
// Flagged rows' final inds are histogrammed here (phase1 counts unflagged).
__global__ __launch_bounds__(256) void rescore_kernel(
    const float* __restrict__ x, const float* __restrict__ embed,
    const float* __restrict__ nhe2, const int* __restrict__ ws_list,
    const int* __restrict__ ws_nflag, int* __restrict__ ws_ind,
    float* __restrict__ out_indf, int* __restrict__ cnt)
{
    __shared__ float xs[128][16];
    __shared__ float redv[4][16];
    __shared__ int   redi[4][16];
    const int tid  = threadIdx.x;
    const int lane = tid & 63;
    const int wave = tid >> 6;
    const int nflag = *ws_nflag;

    for (int g = blockIdx.x; g * 16 < nflag; g += gridDim.x) {
        const int base = g * 16;
        const int cntg = min(16, nflag - base);
        __syncthreads();
        for (int it = 0; it < 2; ++it) {
            int f4 = tid + it * 256;
            int r  = f4 >> 5;
            int d4 = (f4 & 31) * 4;
            int row = ws_list[base + (r < cntg ? r : 0)];
            float4 v = *reinterpret_cast<const float4*>(x + (size_t)row * DIMC + d4);
            xs[d4 + 0][r] = v.x; xs[d4 + 1][r] = v.y;
            xs[d4 + 2][r] = v.z; xs[d4 + 3][r] = v.w;
        }
        __syncthreads();

        float b1[16]; int i1[16];
#pragma unroll
        for (int r = 0; r < 16; ++r) { b1[r] = -3.4e38f; i1[r] = 0; }

#pragma unroll 1
        for (int i = 0; i < 16; ++i) {
            int col = tid + i * 256;
            float acc[16];
#pragma unroll
            for (int r = 0; r < 16; ++r) acc[r] = 0.f;
#pragma unroll 2
            for (int d = 0; d < DIMC; d += 8) {
                float ev[8];
#pragma unroll
                for (int u = 0; u < 8; ++u) ev[u] = embed[(size_t)(d + u) * KC + col];
#pragma unroll
                for (int u = 0; u < 8; ++u) {
                    float4 xa = *reinterpret_cast<const float4*>(&xs[d + u][0]);
                    float4 xb = *reinterpret_cast<const float4*>(&xs[d + u][4]);
                    float4 xc = *reinterpret_cast<const float4*>(&xs[d + u][8]);
                    float4 xd = *reinterpret_cast<const float4*>(&xs[d + u][12]);
                    acc[0]  = fmaf(xa.x, ev[u], acc[0]);  acc[1]  = fmaf(xa.y, ev[u], acc[1]);
                    acc[2]  = fmaf(xa.z, ev[u], acc[2]);  acc[3]  = fmaf(xa.w, ev[u], acc[3]);
                    acc[4]  = fmaf(xb.x, ev[u], acc[4]);  acc[5]  = fmaf(xb.y, ev[u], acc[5]);
                    acc[6]  = fmaf(xb.z, ev[u], acc[6]);  acc[7]  = fmaf(xb.w, ev[u], acc[7]);
                    acc[8]  = fmaf(xc.x, ev[u], acc[8]);  acc[9]  = fmaf(xc.y, ev[u], acc[9]);
                    acc[10] = fmaf(xc.z, ev[u], acc[10]); acc[11] = fmaf(xc.w, ev[u], acc[11]);
                    acc[12] = fmaf(xd.x, ev[u], acc[12]); acc[13] = fmaf(xd.y, ev[u], acc[13]);
                    acc[14] = fmaf(xd.z, ev[u], acc[14]); acc[15] = fmaf(xd.w, ev[u], acc[15]);
                }
            }
            float nh = nhe2[col];
#pragma unroll
            for (int r = 0; r < 16; ++r) {
                float s = acc[r] + nh;
                if (s > b1[r]) { b1[r] = s; i1[r] = col; }
            }
        }
#pragma unroll
        for (int off = 1; off < 64; off <<= 1)
#pragma unroll
            for (int r = 0; r < 16; ++r) {
                float ob = __shfl_xor(b1[r], off, 64);
                int   oi = __shfl_xor(i1[r], off, 64);
                if (ob > b1[r] || (ob == b1[r] && oi < i1[r])) { b1[r] = ob; i1[r] = oi; }
            }
        if (lane == 0)
#pragma unroll
            for (int r = 0; r < 16; ++r) { redv[wave][r] = b1[r]; redi[wave][r] = i1[r]; }
        __syncthreads();
        if (tid < cntg) {
            float bv = redv[0][tid]; int bi = redi[0][tid];
#pragma unroll
            for (int w = 1; w < 4; ++w) {
                float ov = redv[w][tid]; int oi = redi[w][tid];
                if (ov > bv || (ov == bv && oi < bi)) { bv = ov; bi = oi; }
            }
            int row = ws_list[base + tid];
            ws_ind[row]   = bi;
            out_indf[row] = (float)bi;
            atomicAdd(&cnt[bi], 1);                // fused histogram (flagged rows)
        }
    }
}

// ---------------- kernel X: exclusive prefix sum over 4096 counts ----------------
__global__ __launch_bounds__(1024) void scan_kernel(const int* __restrict__ cnt,
                                                    int* __restrict__ start,
                                                    int* __restrict__ cursor) {
    __shared__ int sh[1024];
    const int t = threadIdx.x;
    int4 c = *reinterpret_cast<const int4*>(cnt + t * 4);
    int s = c.x + c.y + c.z + c.w;
    sh[t] = s;
    __syncthreads();
    for (int off = 1; off < 1024; off <<= 1) {
        int v = (t >= off) ? sh[t - off] : 0;
        __syncthreads();
        sh[t] += v;
        __syncthreads();
    }
    int s0 = (t == 0) ? 0 : sh[t - 1];
    start[t * 4 + 0] = s0; cursor[t * 4 + 0] = s0; s0 += c.x;
    start[t * 4 + 1] = s0; cursor[t * 4 + 1] = s0; s0 += c.y;
    start[t * 4 + 2] = s0; cursor[t * 4 + 2] = s0; s0 += c.z;
    start[t * 4 + 3] = s0; cursor[t * 4 + 3] = s0;
}

// ---------------- kernel B: scatter row ids into cluster-sorted order ----------------
__global__ __launch_bounds__(256) void bucket_kernel(const int* __restrict__ ind,
                                                     int* __restrict__ cursor,
                                                     int* __restrict__ sorted) {
    int n = blockIdx.x * 256 + threadIdx.x;
    int p = atomicAdd(&cursor[ind[n]], 1);
    sorted[p] = n;
}

// ---------------- kernel CS v2: per-cluster segmented sum + fused quantize + loss ----------------
__global__ __launch_bounds__(128) void cluster_sum_kernel(
    const float* __restrict__ x, const float* __restrict__ embed,
    const int* __restrict__ sorted, const int* __restrict__ start,
    const int* __restrict__ cnt, float* __restrict__ quant_out,
    float* __restrict__ ws_sum, float* __restrict__ ws_lpart)
{
    const int k = blockIdx.x;
    const int d = threadIdx.x;
    const int s0 = start[k];
    const int c  = cnt[k];
    const float e = embed[(size_t)d * KC + k];
    __shared__ int rows[256];

    float a0 = 0.f, a1 = 0.f, a2 = 0.f, a3 = 0.f;
    float l0 = 0.f, l1 = 0.f, l2 = 0.f, l3 = 0.f;

    for (int base = 0; base < c; base += 256) {
        int m = min(256, c - base);
        __syncthreads();
        if (d < m)        rows[d] = sorted[s0 + base + d];
        if (d + 128 < m)  rows[d + 128] = sorted[s0 + base + d + 128];
        __syncthreads();
        int i = 0;
        for (; i + 4 <= m; i += 4) {
            int r0 = rows[i + 0], r1 = rows[i + 1], r2 = rows[i + 2], r3 = rows[i + 3];
            float x0 = x[(size_t)r0 * DIMC + d];
            float x1 = x[(size_t)r1 * DIMC + d];
            float x2 = x[(size_t)r2 * DIMC + d];
            float x3 = x[(size_t)r3 * DIMC + d];
            float d0 = e - x0, d1 = e - x1, d2 = e - x2, d3 = e - x3;
            a0 += x0; a1 += x1; a2 += x2; a3 += x3;
            l0 = fmaf(d0, d0, l0); l1 = fmaf(d1, d1, l1);
            l2 = fmaf(d2, d2, l2); l3 = fmaf(d3, d3, l3);
            quant_out[(size_t)r0 * DIMC + d] = x0 + d0;
            quant_out[(size_t)r1 * DIMC + d] = x1 + d1;
            quant_out[(size_t)r2 * DIMC + d] = x2 + d2;
            quant_out[(size_t)r3 * DIMC + d] = x3 + d3;
        }
        for (; i < m; ++i) {
            int r0 = rows[i];
            float x0 = x[(size_t)r0 * DIMC + d];
            float d0 = e - x0;
            a0 += x0;
            l0 = fmaf(d0, d0, l0);
            quant_out[(size_t)r0 * DIMC + d] = x0 + d0;
        }
    }
    float acc  = (a0 + a1) + (a2 + a3);
    float loss = (l0 + l1) + (l2 + l3);
    ws_sum[(size_t)d * KC + k] = acc;

#pragma unroll
    for (int off = 32; off >= 1; off >>= 1) loss += __shfl_down(loss, off, 64);
    __shared__ float red[2];
    if ((d & 63) == 0) red[d >> 6] = loss;
    __syncthreads();
    if (d == 0) ws_lpart[k] = red[0] + red[1];
}

// ---------------- kernel D: cluster_size_new, n_small, loss, inverse norm ----------------
__global__ __launch_bounds__(1024) void finalize_kernel(
    const float* __restrict__ cs, const int* __restrict__ cnt,
    const float* __restrict__ ws_lpart,
    float* __restrict__ out_loss, float* __restrict__ out_nsmall,
    float* __restrict__ out_csn, float* __restrict__ ws_inv)
{
    const int tid = threadIdx.x;
    float csn_loc[4];
    float lsum = 0.f, lsmall = 0.f, lloss = 0.f;
#pragma unroll
    for (int i = 0; i < 4; ++i) {
        int k = tid + i * 1024;
        float csn = cs[k] * DECAYC + OMDECAY * (float)cnt[k];
        out_csn[k] = csn;
        csn_loc[i] = csn;
        lsum += csn;
        lsmall += (csn < 1.f) ? 1.f : 0.f;
        lloss += ws_lpart[k];
    }
#pragma unroll
    for (int off = 32; off >= 1; off >>= 1) {
        lsum   += __shfl_down(lsum, off, 64);
        lsmall += __shfl_down(lsmall, off, 64);
        lloss  += __shfl_down(lloss, off, 64);
    }
    __shared__ float sh1[16], sh2[16], sh3[16];
    __shared__ float ntot_s;
    if ((tid & 63) == 0) { sh1[tid >> 6] = lsum; sh2[tid >> 6] = lsmall; sh3[tid >> 6] = lloss; }
    __syncthreads();
    if (tid == 0) {
        float tot = 0.f, sm = 0.f, lo = 0.f;
        for (int w = 0; w < 16; ++w) { tot += sh1[w]; sm += sh2[w]; lo += sh3[w]; }
        ntot_s = tot;
        out_nsmall[0] = sm;
        out_loss[0] = lo * (1.0f / ((float)NVEC * (float)DIMC));
    }
    __syncthreads();
    float ntot = ntot_s;
    float scale = (ntot + (float)KC * EPSC) / ntot;
#pragma unroll
    for (int i = 0; i < 4; ++i) {
        int k = tid + i * 1024;
        ws_inv[k] = scale / (csn_loc[i] + EPSC);
    }
}

// ---------------- kernel E: embed_avg_new and embed_new ----------------
__global__ __launch_bounds__(256) void ema_embed_kernel(
    const float* __restrict__ ea, const float* __restrict__ ws_sum,
    const float* __restrict__ ws_inv, float* __restrict__ out_embed_new,
    float* __restrict__ out_ean)
{
    size_t i4 = ((size_t)blockIdx.x * 256 + threadIdx.x) * 4;
    float4 a = *reinterpret_cast<const float4*>(ea + i4);
    float4 s = *reinterpret_cast<const float4*>(ws_sum + i4);
    int k = (int)(i4 & (KC - 1));
    float4 inv = *reinterpret_cast<const float4*>(ws_inv + k);
    float e0 = a.x * DECAYC + OMDECAY * s.x;
    float e1 = a.y * DECAYC + OMDECAY * s.y;
    float e2 = a.z * DECAYC + OMDECAY * s.z;
    float e3 = a.w * DECAYC + OMDECAY * s.w;
    *reinterpret_cast<float2*>(out_ean + i4)     = make_float2(e0, e1);
    *reinterpret_cast<float2*>(out_ean + i4 + 2) = make_float2(e2, e3);
    *reinterpret_cast<float2*>(out_embed_new + i4)     = make_float2(e0 * inv.x, e1 * inv.y);
    *reinterpret_cast<float2*>(out_embed_new + i4 + 2) = make_float2(e2 * inv.z, e3 * inv.w);
}

extern "C" void kernel_launch(void* const* d_in, const int* in_sizes, int n_in,
                              void* d_out, int out_size, void* d_ws, size_t ws_size,
                              hipStream_t stream) {
    const float* x     = (const float*)d_in[0];   // [N, D]
    const float* embed = (const float*)d_in[1];   // [D, K]
    const float* cs    = (const float*)d_in[2];   // [K]
    const float* ea    = (const float*)d_in[3];   // [D, K]

    float* out  = (float*)d_out;
    float* out0 = out;                 // quantize_st   [N, D]
    float* out1 = out + 16777216;      // quant_loss
    float* out2 = out + 16777217;      // n_small
    float* out3 = out + 16777218;      // embed_ind [N]
    float* out4 = out + 16908290;      // embed_new [D, K]
    float* out5 = out + 17432578;      // cluster_size_new [K]
    float* out6 = out + 17436674;      // embed_avg_new [D, K]

    // workspace layout (float units)
    float* ws       = (float*)d_ws;
    float* ws_sum   = ws;                    // 524288
    int*   ws_nflag = (int*)(ws + 528385);   // 1 (zeroed)
    float* ws_inv   = ws + 528388;           // 4096
    float* nhe2     = ws + 532484;           // 4096
    int*   ws_ind   = (int*)(ws + 1060868);  // 131072
    int*   ws_cnt_i = (int*)(ws + 1191940);  // 4096 (old ws_gap slot; live DURING phase1)
    int*   ws_list  = (int*)(ws + 1323012);  // 131072
    __bf16* ehT     = (__bf16*)(ws + 1454084);
    __bf16* elT     = (__bf16*)(ws + 1716228);
    // aliases (used only AFTER phase1 is done with ehT/elT):
    int*   ws_sorted = (int*)(ws + 1454084);
    int*   ws_start  = (int*)(ws + 1720324);
    int*   ws_cursor = (int*)(ws + 1724420);
    float* ws_lpart  = ws + 1728516;

    hipMemsetAsync(ws_nflag, 0, sizeof(int), stream);
    hipMemsetAsync(ws_cnt_i, 0, KC * sizeof(int), stream);

    hipLaunchKernelGGL(split_e_kernel,   dim3(KC / 64), dim3(256), 0, stream,
                       embed, ehT, elT, nhe2);
    hipLaunchKernelGGL(phase1_kernel,    dim3(NVEC / 128), dim3(256), 0, stream,
                       x, ehT, elT, nhe2, out3, ws_ind, ws_nflag, ws_list, ws_cnt_i);
    hipLaunchKernelGGL(rescore_kernel,   dim3(512), dim3(256), 0, stream,
                       x, embed, nhe2, ws_list, ws_nflag, ws_ind, out3, ws_cnt_i);

    // counting sort by cluster id (aliases safe: ehT/elT dead after phase1)
    hipLaunchKernelGGL(scan_kernel,   dim3(1), dim3(1024), 0, stream, ws_cnt_i, ws_start, ws_cursor);
    hipLaunchKernelGGL(bucket_kernel, dim3(NVEC / 256), dim3(256), 0, stream,
                       ws_ind, ws_cursor, ws_sorted);
    hipLaunchKernelGGL(cluster_sum_kernel, dim3(KC), dim3(128), 0, stream,
                       x, embed, ws_sorted, ws_start, ws_cnt_i, out0, ws_sum, ws_lpart);

    hipLaunchKernelGGL(finalize_kernel, dim3(1), dim3(1024), 0, stream,
                       cs, ws_cnt_i, ws_lpart, out1, out2, out5, ws_inv);
    hipLaunchKernelGGL(ema_embed_kernel, dim3((DIMC * KC) / 1024), dim3(256), 0, stream,
                       ea, ws_sum, ws_inv, out4, out6);
}

// Round 5
// 868.733 us; speedup vs baseline: 1.1770x; 1.1770x over previous
//
#include <hip/hip_runtime.h>

// Problem constants (match reference)
constexpr int   NVEC  = 131072;   // N
constexpr int   DIMC  = 128;      // latent dim
constexpr int   KC    = 4096;     // codebook size
constexpr float DECAYC = 0.99f;
constexpr float OMDECAY = 0.01f;
constexpr float EPSC  = 1e-5f;
// 3-term split product (ah.bh + al.bh + ah.bl): score error = al.bl,
// |err| <= 2^-16 * sum|x||e| ~ 1.3e-3 worst case. MARGIN = 16x worst case.
constexpr float MARGIN = 0.02f;

typedef __bf16 v8bf __attribute__((ext_vector_type(8)));
typedef float  v4f  __attribute__((ext_vector_type(4)));

// Async global->LDS 16B copy: dest = wave-uniform LDS base + lane*16.
__device__ __forceinline__ void async_copy16(const void* gp, void* lds_wave_base, int lane) {
#if __has_builtin(__builtin_amdgcn_global_load_lds)
    __builtin_amdgcn_global_load_lds(
        (const __attribute__((address_space(1))) unsigned int*)gp,
        (__attribute__((address_space(3))) unsigned int*)lds_wave_base, 16, 0, 0);
#else
    ((v8bf*)lds_wave_base)[lane] = *(const v8bf*)gp;
#endif
}

// ---------------- kernel S: split embed into bf16 hi/lo (transposed) + fused colnorm ----------------
__global__ __launch_bounds__(256) void split_e_kernel(const float* __restrict__ embed,
                                                      __bf16* __restrict__ ehT,
                                                      __bf16* __restrict__ elT,
                                                      float* __restrict__ nhe2) {
    __shared__ __bf16 sh_h[64 * 130];
    __shared__ __bf16 sh_l[64 * 130];
    __shared__ float  sh_n[4][64];
    const int tid = threadIdx.x;
    const int kbase = blockIdx.x * 64;
    const int kloc = tid & 63;
    float nacc = 0.f;
    for (int it = 0; it < 32; ++it) {
        int d = it * 4 + (tid >> 6);
        float v = embed[(size_t)d * KC + kbase + kloc];   // coalesced in k
        __bf16 h = (__bf16)v;
        __bf16 l = (__bf16)(v - (float)h);
        sh_h[kloc * 130 + d] = h;
        sh_l[kloc * 130 + d] = l;
        nacc = fmaf(v, v, nacc);
    }
    sh_n[tid >> 6][kloc] = nacc;
    __syncthreads();
    if (tid < 64)
        nhe2[kbase + tid] = -0.5f * (sh_n[0][tid] + sh_n[1][tid] + sh_n[2][tid] + sh_n[3][tid]);
    for (int it = 0; it < 32; ++it) {
        int idx = it * 256 + tid;
        int k = idx >> 7;
        int d = idx & 127;
        ehT[(size_t)(kbase + k) * DIMC + d] = sh_h[k * 130 + d];
        elT[(size_t)(kbase + k) * DIMC + d] = sh_l[k * 130 + d];
    }
}

// ---------------- kernel P1 v5 (REVERT, proven 356 us): MFMA split-bf16 GEMM + per-row top-2 ----
// Round-3 (explicit dbuf pipeline) and round-4 (32x32 single-chain) both REGRESSED:
// the implicit inter-wave overlap at ~3 blocks/CU with two interleaved acc chains
// is the best schedule found for this structure.
// 4 waves/block; wave owns 32 rows (2 x 16-row tiles).
// LDS: one 32 KB array of 16 B granules, SLOT-MAJOR: (ct, g, c) at ct*256 + g*16 + c.
// Fragment reads: lane l reads E[ct*256 + s*64 + l] -> stride-1 across the wave
// (conflict-free; measured SQ_LDS_BANK_CONFLICT = 0), ct/s fold into the ds immediate.
// -0.5|e|^2 folded into the MFMA accumulator init.
__global__ __launch_bounds__(256, 2) void phase1_kernel(
    const float* __restrict__ x, const __bf16* __restrict__ ehT,
    const __bf16* __restrict__ elT, const float* __restrict__ nhe2,
    float* __restrict__ out_indf, int* __restrict__ ws_ind, float* __restrict__ ws_gap)
{
    __shared__ v8bf E[2048];    // [0..1023] = hi, [1024..2047] = lo
    const int tid  = threadIdx.x;
    const int wave = tid >> 6;
    const int lane = tid & 63;
    const int c    = lane & 15;     // MFMA m / n index
    const int q    = lane >> 4;     // quad
    const int rowBase = blockIdx.x * 128 + wave * 32;

    // A fragments: 2 row-tiles x 4 k-slices, hi + exact residual lo
    v8bf ah[2][4], al[2][4];
#pragma unroll
    for (int t = 0; t < 2; ++t)
#pragma unroll
        for (int s = 0; s < 4; ++s) {
            const float* p = x + (size_t)(rowBase + t * 16 + c) * DIMC + s * 32 + q * 8;
            float4 v0 = *reinterpret_cast<const float4*>(p);
            float4 v1 = *reinterpret_cast<const float4*>(p + 4);
            float vv[8] = {v0.x, v0.y, v0.z, v0.w, v1.x, v1.y, v1.z, v1.w};
            v8bf h, l;
#pragma unroll
            for (int j = 0; j < 8; ++j) {
                __bf16 hh = (__bf16)vv[j];
                h[j] = hh;
                l[j] = (__bf16)(vv[j] - (float)hh);
            }
            ah[t][s] = h; al[t][s] = l;
        }

    // Staging source pointers (chunk-invariant per-thread offset; advance by stride).
    // Dest granule D = it*256 + tid holds (ct = it, g = tid>>4, c = tid&15),
    // i.e. source col = chunkbase + it*16 + (tid&15), k-slot = tid>>4.
    const __bf16* ph = ehT + (size_t)(tid & 15) * DIMC + (tid >> 4) * 8;
    const __bf16* pl = elT + (size_t)(tid & 15) * DIMC + (tid >> 4) * 8;

    float b1[8], b2[8]; int i1[8];
#pragma unroll
    for (int s = 0; s < 8; ++s) { b1[s] = -3.4e38f; b2[s] = -3.4e38f; i1[s] = 0; }

    for (int chunk = 0; chunk < KC / 64; ++chunk) {
        // preload -0.5|e|^2 for this chunk's 4 col-tiles (L2-hot, hides under staging)
        float nhc[4];
#pragma unroll
        for (int t4 = 0; t4 < 4; ++t4) nhc[t4] = nhe2[chunk * 64 + t4 * 16 + c];
#pragma unroll
        for (int it = 0; it < 4; ++it) {
            async_copy16(ph + (size_t)it * 16 * DIMC, &E[it * 256 + wave * 64], lane);
            async_copy16(pl + (size_t)it * 16 * DIMC, &E[1024 + it * 256 + wave * 64], lane);
        }
        ph += (size_t)64 * DIMC;
        pl += (size_t)64 * DIMC;
        __syncthreads();

#pragma unroll
        for (int ct = 0; ct < 4; ++ct) {
            const float nh = nhc[ct];
            v4f acc0 = {nh, nh, nh, nh};
            v4f acc1 = {nh, nh, nh, nh};
#pragma unroll
            for (int s = 0; s < 4; ++s) {
                v8bf bh = E[ct * 256 + s * 64 + lane];
                v8bf bl = E[1024 + ct * 256 + s * 64 + lane];
                acc0 = __builtin_amdgcn_mfma_f32_16x16x32_bf16(ah[0][s], bh, acc0, 0, 0, 0);
                acc1 = __builtin_amdgcn_mfma_f32_16x16x32_bf16(ah[1][s], bh, acc1, 0, 0, 0);
                acc0 = __builtin_amdgcn_mfma_f32_16x16x32_bf16(al[0][s], bh, acc0, 0, 0, 0);
                acc1 = __builtin_amdgcn_mfma_f32_16x16x32_bf16(al[1][s], bh, acc1, 0, 0, 0);
                acc0 = __builtin_amdgcn_mfma_f32_16x16x32_bf16(ah[0][s], bl, acc0, 0, 0, 0);
                acc1 = __builtin_amdgcn_mfma_f32_16x16x32_bf16(ah[1][s], bl, acc1, 0, 0, 0);
            }
            const int colG = chunk * 64 + ct * 16 + c;
#pragma unroll
            for (int r = 0; r < 4; ++r) {
                float sc = acc0[r];
                float ob = b1[r];
                b2[r] = __builtin_amdgcn_fmed3f(ob, b2[r], sc);  // exact 2nd-best update
                b1[r] = fmaxf(ob, sc);
                i1[r] = (sc > ob) ? colG : i1[r];                 // strict: tie keeps earlier col
                float sc1 = acc1[r];
                float ob1 = b1[4 + r];
                b2[4 + r] = __builtin_amdgcn_fmed3f(ob1, b2[4 + r], sc1);
                b1[4 + r] = fmaxf(ob1, sc1);
                i1[4 + r] = (sc1 > ob1) ? colG : i1[4 + r];
            }
        }
        __syncthreads();
    }

    // top-2 merge across the 16 col-lanes of each row group (tie -> lowest index)
#pragma unroll
    for (int off = 1; off < 16; off <<= 1) {
#pragma unroll
        for (int s = 0; s < 8; ++s) {
            float ob1 = __shfl_xor(b1[s], off, 64);
            int   oi1 = __shfl_xor(i1[s], off, 64);
            float ob2 = __shfl_xor(b2[s], off, 64);
            if (ob1 > b1[s] || (ob1 == b1[s] && oi1 < i1[s])) {
                b2[s] = fmaxf(b1[s], ob2); b1[s] = ob1; i1[s] = oi1;
            } else {
                b2[s] = fmaxf(b2[s], ob1);
            }
        }
    }
    if (c == 0) {
#pragma unroll
        for (int s = 0; s < 8; ++s) {
            int t = s >> 2, r = s & 3;
            int row = rowBase + t * 16 + q * 4 + r;
            ws_ind[row]   = i1[s];
            out_indf[row] = (float)i1[s];
            ws_gap[row]   = b1[s] - b2[s];
        }
    }
}

// ---------------- kernel FH: fused flag-compaction + histogram (unflagged rows) ----------------
// Flagged rows (gap < MARGIN) go to ws_list for exact rescore; their final ind is
// histogrammed by rescore's tail. Unflagged rows are counted here (ind is final).
__global__ __launch_bounds__(256) void fh_kernel(const float* __restrict__ ws_gap,
                                                 const int* __restrict__ ws_ind,
                                                 int* __restrict__ ws_nflag,
                                                 int* __restrict__ ws_list,
                                                 int* __restrict__ cnt) {
    int n = blockIdx.x * 256 + threadIdx.x;
    if (ws_gap[n] < MARGIN) {
        int p = atomicAdd(ws_nflag, 1);
        ws_list[p] = n;
    } else {
        atomicAdd(&cnt[ws_ind[n]], 1);
    }
}

// ---------------- kernel R v2: exact fp32 rescore of flagged rows (16 rows/block) ----------------
// ev loads batched 8-wide: cuts the serial d-chain of 1 VMEM load per 16 FMAs
// (latency-bound at L2/L3) to 8 in-flight loads per 128 FMAs.
// Flagged rows' final inds are histogrammed here (fh counts unflagged).
__global__ __launch_bounds__(256) void rescore_kernel(
    const float* __restrict__ x, const float* __restrict__ embed,
    const float* __restrict__ nhe2, const int* __restrict__ ws_list,
    const int* __restrict__ ws_nflag, int* __restrict__ ws_ind,
    float* __restrict__ out_indf, int* __restrict__ cnt)
{
    __shared__ float xs[128][16];
    __shared__ float redv[4][16];
    __shared__ int   redi[4][16];
    const int tid  = threadIdx.x;
    const int lane = tid & 63;
    const int wave = tid >> 6;
    const int nflag = *ws_nflag;

    for (int g = blockIdx.x; g * 16 < nflag; g += gridDim.x) {
        const int base = g * 16;
        const int cntg = min(16, nflag - base);
        __syncthreads();
        for (int it = 0; it < 2; ++it) {
            int f4 = tid + it * 256;
            int r  = f4 >> 5;
            int d4 = (f4 & 31) * 4;
            int row = ws_list[base + (r < cntg ? r : 0)];
            float4 v = *reinterpret_cast<const float4*>(x + (size_t)row * DIMC + d4);
            xs[d4 + 0][r] = v.x; xs[d4 + 1][r] = v.y;
            xs[d4 + 2][r] = v.z; xs[d4 + 3][r] = v.w;
        }
        __syncthreads();

        float b1[16]; int i1[16];
#pragma unroll
        for (int r = 0; r < 16; ++r) { b1[r] = -3.4e38f; i1[r] = 0; }

#pragma unroll 1
        for (int i = 0; i < 16; ++i) {
            int col = tid + i * 256;
            float acc[16];
#pragma unroll
            for (int r = 0; r < 16; ++r) acc[r] = 0.f;
#pragma unroll 2
            for (int d = 0; d < DIMC; d += 8) {
                float ev[8];
#pragma unroll
                for (int u = 0; u < 8; ++u) ev[u] = embed[(size_t)(d + u) * KC + col];
#pragma unroll
                for (int u = 0; u < 8; ++u) {
                    float4 xa = *reinterpret_cast<const float4*>(&xs[d + u][0]);
                    float4 xb = *reinterpret_cast<const float4*>(&xs[d + u][4]);
                    float4 xc = *reinterpret_cast<const float4*>(&xs[d + u][8]);
                    float4 xd = *reinterpret_cast<const float4*>(&xs[d + u][12]);
                    acc[0]  = fmaf(xa.x, ev[u], acc[0]);  acc[1]  = fmaf(xa.y, ev[u], acc[1]);
                    acc[2]  = fmaf(xa.z, ev[u], acc[2]);  acc[3]  = fmaf(xa.w, ev[u], acc[3]);
                    acc[4]  = fmaf(xb.x, ev[u], acc[4]);  acc[5]  = fmaf(xb.y, ev[u], acc[5]);
                    acc[6]  = fmaf(xb.z, ev[u], acc[6]);  acc[7]  = fmaf(xb.w, ev[u], acc[7]);
                    acc[8]  = fmaf(xc.x, ev[u], acc[8]);  acc[9]  = fmaf(xc.y, ev[u], acc[9]);
                    acc[10] = fmaf(xc.z, ev[u], acc[10]); acc[11] = fmaf(xc.w, ev[u], acc[11]);
                    acc[12] = fmaf(xd.x, ev[u], acc[12]); acc[13] = fmaf(xd.y, ev[u], acc[13]);
                    acc[14] = fmaf(xd.z, ev[u], acc[14]); acc[15] = fmaf(xd.w, ev[u], acc[15]);
                }
            }
            float nh = nhe2[col];
#pragma unroll
            for (int r = 0; r < 16; ++r) {
                float s = acc[r] + nh;
                if (s > b1[r]) { b1[r] = s; i1[r] = col; }
            }
        }
#pragma unroll
        for (int off = 1; off < 64; off <<= 1)
#pragma unroll
            for (int r = 0; r < 16; ++r) {
                float ob = __shfl_xor(b1[r], off, 64);
                int   oi = __shfl_xor(i1[r], off, 64);
                if (ob > b1[r] || (ob == b1[r] && oi < i1[r])) { b1[r] = ob; i1[r] = oi; }
            }
        if (lane == 0)
#pragma unroll
            for (int r = 0; r < 16; ++r) { redv[wave][r] = b1[r]; redi[wave][r] = i1[r]; }
        __syncthreads();
        if (tid < cntg) {
            float bv = redv[0][tid]; int bi = redi[0][tid];
#pragma unroll
            for (int w = 1; w < 4; ++w) {
                float ov = redv[w][tid]; int oi = redi[w][tid];
                if (ov > bv || (ov == bv && oi < bi)) { bv = ov; bi = oi; }
            }
            int row = ws_list[base + tid];
            ws_ind[row]   = bi;
            out_indf[row] = (float)bi;
            atomicAdd(&cnt[bi], 1);                // fused histogram (flagged rows)
        }
    }
}

// ---------------- kernel X: exclusive prefix sum over 4096 counts ----------------
__global__ __launch_bounds__(1024) void scan_kernel(const int* __restrict__ cnt,
                                                    int* __restrict__ start,
                                                    int* __restrict__ cursor) {
    __shared__ int sh[1024];
    const int t = threadIdx.x;
    int4 c = *reinterpret_cast<const int4*>(cnt + t * 4);
    int s = c.x + c.y + c.z + c.w;
    sh[t] = s;
    __syncthreads();
    for (int off = 1; off < 1024; off <<= 1) {
        int v = (t >= off) ? sh[t - off] : 0;
        __syncthreads();
        sh[t] += v;
        __syncthreads();
    }
    int s0 = (t == 0) ? 0 : sh[t - 1];
    start[t * 4 + 0] = s0; cursor[t * 4 + 0] = s0; s0 += c.x;
    start[t * 4 + 1] = s0; cursor[t * 4 + 1] = s0; s0 += c.y;
    start[t * 4 + 2] = s0; cursor[t * 4 + 2] = s0; s0 += c.z;
    start[t * 4 + 3] = s0; cursor[t * 4 + 3] = s0;
}

// ---------------- kernel B: scatter row ids into cluster-sorted order ----------------
__global__ __launch_bounds__(256) void bucket_kernel(const int* __restrict__ ind,
                                                     int* __restrict__ cursor,
                                                     int* __restrict__ sorted) {
    int n = blockIdx.x * 256 + threadIdx.x;
    int p = atomicAdd(&cursor[ind[n]], 1);
    sorted[p] = n;
}

// ---------------- kernel CS v2: per-cluster segmented sum + fused quantize + loss ----------------
__global__ __launch_bounds__(128) void cluster_sum_kernel(
    const float* __restrict__ x, const float* __restrict__ embed,
    const int* __restrict__ sorted, const int* __restrict__ start,
    const int* __restrict__ cnt, float* __restrict__ quant_out,
    float* __restrict__ ws_sum, float* __restrict__ ws_lpart)
{
    const int k = blockIdx.x;
    const int d = threadIdx.x;
    const int s0 = start[k];
    const int c  = cnt[k];
    const float e = embed[(size_t)d * KC + k];
    __shared__ int rows[256];

    float a0 = 0.f, a1 = 0.f, a2 = 0.f, a3 = 0.f;
    float l0 = 0.f, l1 = 0.f, l2 = 0.f, l3 = 0.f;

    for (int base = 0; base < c; base += 256) {
        int m = min(256, c - base);
        __syncthreads();
        if (d < m)        rows[d] = sorted[s0 + base + d];
        if (d + 128 < m)  rows[d + 128] = sorted[s0 + base + d + 128];
        __syncthreads();
        int i = 0;
        for (; i + 4 <= m; i += 4) {
            int r0 = rows[i + 0], r1 = rows[i + 1], r2 = rows[i + 2], r3 = rows[i + 3];
            float x0 = x[(size_t)r0 * DIMC + d];
            float x1 = x[(size_t)r1 * DIMC + d];
            float x2 = x[(size_t)r2 * DIMC + d];
            float x3 = x[(size_t)r3 * DIMC + d];
            float d0 = e - x0, d1 = e - x1, d2 = e - x2, d3 = e - x3;
            a0 += x0; a1 += x1; a2 += x2; a3 += x3;
            l0 = fmaf(d0, d0, l0); l1 = fmaf(d1, d1, l1);
            l2 = fmaf(d2, d2, l2); l3 = fmaf(d3, d3, l3);
            quant_out[(size_t)r0 * DIMC + d] = x0 + d0;
            quant_out[(size_t)r1 * DIMC + d] = x1 + d1;
            quant_out[(size_t)r2 * DIMC + d] = x2 + d2;
            quant_out[(size_t)r3 * DIMC + d] = x3 + d3;
        }
        for (; i < m; ++i) {
            int r0 = rows[i];
            float x0 = x[(size_t)r0 * DIMC + d];
            float d0 = e - x0;
            a0 += x0;
            l0 = fmaf(d0, d0, l0);
            quant_out[(size_t)r0 * DIMC + d] = x0 + d0;
        }
    }
    float acc  = (a0 + a1) + (a2 + a3);
    float loss = (l0 + l1) + (l2 + l3);
    ws_sum[(size_t)d * KC + k] = acc;

#pragma unroll
    for (int off = 32; off >= 1; off >>= 1) loss += __shfl_down(loss, off, 64);
    __shared__ float red[2];
    if ((d & 63) == 0) red[d >> 6] = loss;
    __syncthreads();
    if (d == 0) ws_lpart[k] = red[0] + red[1];
}

// ---------------- kernel D: cluster_size_new, n_small, loss, inverse norm ----------------
__global__ __launch_bounds__(1024) void finalize_kernel(
    const float* __restrict__ cs, const int* __restrict__ cnt,
    const float* __restrict__ ws_lpart,
    float* __restrict__ out_loss, float* __restrict__ out_nsmall,
    float* __restrict__ out_csn, float* __restrict__ ws_inv)
{
    const int tid = threadIdx.x;
    float csn_loc[4];
    float lsum = 0.f, lsmall = 0.f, lloss = 0.f;
#pragma unroll
    for (int i = 0; i < 4; ++i) {
        int k = tid + i * 1024;
        float csn = cs[k] * DECAYC + OMDECAY * (float)cnt[k];
        out_csn[k] = csn;
        csn_loc[i] = csn;
        lsum += csn;
        lsmall += (csn < 1.f) ? 1.f : 0.f;
        lloss += ws_lpart[k];
    }
#pragma unroll
    for (int off = 32; off >= 1; off >>= 1) {
        lsum   += __shfl_down(lsum, off, 64);
        lsmall += __shfl_down(lsmall, off, 64);
        lloss  += __shfl_down(lloss, off, 64);
    }
    __shared__ float sh1[16], sh2[16], sh3[16];
    __shared__ float ntot_s;
    if ((tid & 63) == 0) { sh1[tid >> 6] = lsum; sh2[tid >> 6] = lsmall; sh3[tid >> 6] = lloss; }
    __syncthreads();
    if (tid == 0) {
        float tot = 0.f, sm = 0.f, lo = 0.f;
        for (int w = 0; w < 16; ++w) { tot += sh1[w]; sm += sh2[w]; lo += sh3[w]; }
        ntot_s = tot;
        out_nsmall[0] = sm;
        out_loss[0] = lo * (1.0f / ((float)NVEC * (float)DIMC));
    }
    __syncthreads();
    float ntot = ntot_s;
    float scale = (ntot + (float)KC * EPSC) / ntot;
#pragma unroll
    for (int i = 0; i < 4; ++i) {
        int k = tid + i * 1024;
        ws_inv[k] = scale / (csn_loc[i] + EPSC);
    }
}

// ---------------- kernel E: embed_avg_new and embed_new ----------------
__global__ __launch_bounds__(256) void ema_embed_kernel(
    const float* __restrict__ ea, const float* __restrict__ ws_sum,
    const float* __restrict__ ws_inv, float* __restrict__ out_embed_new,
    float* __restrict__ out_ean)
{
    size_t i4 = ((size_t)blockIdx.x * 256 + threadIdx.x) * 4;
    float4 a = *reinterpret_cast<const float4*>(ea + i4);
    float4 s = *reinterpret_cast<const float4*>(ws_sum + i4);
    int k = (int)(i4 & (KC - 1));
    float4 inv = *reinterpret_cast<const float4*>(ws_inv + k);
    float e0 = a.x * DECAYC + OMDECAY * s.x;
    float e1 = a.y * DECAYC + OMDECAY * s.y;
    float e2 = a.z * DECAYC + OMDECAY * s.z;
    float e3 = a.w * DECAYC + OMDECAY * s.w;
    *reinterpret_cast<float2*>(out_ean + i4)     = make_float2(e0, e1);
    *reinterpret_cast<float2*>(out_ean + i4 + 2) = make_float2(e2, e3);
    *reinterpret_cast<float2*>(out_embed_new + i4)     = make_float2(e0 * inv.x, e1 * inv.y);
    *reinterpret_cast<float2*>(out_embed_new + i4 + 2) = make_float2(e2 * inv.z, e3 * inv.w);
}

extern "C" void kernel_launch(void* const* d_in, const int* in_sizes, int n_in,
                              void* d_out, int out_size, void* d_ws, size_t ws_size,
                              hipStream_t stream) {
    const float* x     = (const float*)d_in[0];   // [N, D]
    const float* embed = (const float*)d_in[1];   // [D, K]
    const float* cs    = (const float*)d_in[2];   // [K]
    const float* ea    = (const float*)d_in[3];   // [D, K]

    float* out  = (float*)d_out;
    float* out0 = out;                 // quantize_st   [N, D]
    float* out1 = out + 16777216;      // quant_loss
    float* out2 = out + 16777217;      // n_small
    float* out3 = out + 16777218;      // embed_ind [N]
    float* out4 = out + 16908290;      // embed_new [D, K]
    float* out5 = out + 17432578;      // cluster_size_new [K]
    float* out6 = out + 17436674;      // embed_avg_new [D, K]

    // workspace layout (float units)
    float* ws       = (float*)d_ws;
    float* ws_sum   = ws;                    // 524288
    int*   ws_nflag = (int*)(ws + 528385);   // 1 (zeroed)
    float* ws_inv   = ws + 528388;           // 4096
    float* nhe2     = ws + 532484;           // 4096
    int*   ws_ind   = (int*)(ws + 1060868);  // 131072
    float* ws_gap   = ws + 1191940;          // 131072
    int*   ws_list  = (int*)(ws + 1323012);  // 131072
    __bf16* ehT     = (__bf16*)(ws + 1454084);
    __bf16* elT     = (__bf16*)(ws + 1716228);
    // aliases (used only AFTER phase1 is done with ehT/elT; stream-ordered):
    int*   ws_sorted = (int*)(ws + 1454084);
    int*   ws_cnt_i  = (int*)(ws + 1716228);
    int*   ws_start  = (int*)(ws + 1720324);
    int*   ws_cursor = (int*)(ws + 1724420);
    float* ws_lpart  = ws + 1728516;

    hipMemsetAsync(ws_nflag, 0, sizeof(int), stream);

    hipLaunchKernelGGL(split_e_kernel,   dim3(KC / 64), dim3(256), 0, stream,
                       embed, ehT, elT, nhe2);
    hipLaunchKernelGGL(phase1_kernel,    dim3(NVEC / 128), dim3(256), 0, stream,
                       x, ehT, elT, nhe2, out3, ws_ind, ws_gap);

    // cnt memset AFTER phase1 in stream order (it aliases elT)
    hipMemsetAsync(ws_cnt_i, 0, KC * sizeof(int), stream);
    hipLaunchKernelGGL(fh_kernel,        dim3(NVEC / 256), dim3(256), 0, stream,
                       ws_gap, ws_ind, ws_nflag, ws_list, ws_cnt_i);
    hipLaunchKernelGGL(rescore_kernel,   dim3(512), dim3(256), 0, stream,
                       x, embed, nhe2, ws_list, ws_nflag, ws_ind, out3, ws_cnt_i);

    // counting sort by cluster id (aliases safe: ehT/elT dead after phase1)
    hipLaunchKernelGGL(scan_kernel,   dim3(1), dim3(1024), 0, stream, ws_cnt_i, ws_start, ws_cursor);
    hipLaunchKernelGGL(bucket_kernel, dim3(NVEC / 256), dim3(256), 0, stream,
                       ws_ind, ws_cursor, ws_sorted);
    hipLaunchKernelGGL(cluster_sum_kernel, dim3(KC), dim3(128), 0, stream,
                       x, embed, ws_sorted, ws_start, ws_cnt_i, out0, ws_sum, ws_lpart);

    hipLaunchKernelGGL(finalize_kernel, dim3(1), dim3(1024), 0, stream,
                       cs, ws_cnt_i, ws_lpart, out1, out2, out5, ws_inv);
    hipLaunchKernelGGL(ema_embed_kernel, dim3((DIMC * KC) / 1024), dim3(256), 0, stream,
                       ea, ws_sum, ws_inv, out4, out6);
}